// Round 3
// baseline (1525.214 us; speedup 1.0000x reference)
//
#include <hip/hip_runtime.h>
#include <hip/hip_bf16.h>
#include <cstdint>

#define B_ 256
#define T_ 512
#define F_ 128
#define H_ 128
#define G3_ 384
#define R_ 8
#define K_ 64

__device__ __forceinline__ float sigm(float x) { return 1.f / (1.f + __expf(-x)); }
__device__ __forceinline__ float tanh_f(float x) { return 1.f - 2.f / (1.f + __expf(2.f * x)); }

// C[m][n] = sum_k A[m][k] * W[n][k] + bias[n];  M = B*T, N = 384, K = 128
__global__ __launch_bounds__(256) void gemm_gi(const float* __restrict__ A,
                                               const float* __restrict__ W,
                                               const float* __restrict__ bias,
                                               float* __restrict__ C)
{
    __shared__ alignas(16) float As[32][68];
    __shared__ alignas(16) float Bs[32][68];
    const int tid = threadIdx.x;
    const int tx = tid & 15, ty = tid >> 4;
    const size_t m0 = (size_t)blockIdx.y * 64;
    const int n0 = blockIdx.x * 64;

    float acc[4][4] = {};

    for (int kb = 0; kb < 128; kb += 32) {
        #pragma unroll
        for (int it = 0; it < 2; ++it) {
            int idx = tid + it * 256;
            int row = idx >> 3, kq = idx & 7;
            float4 av = *(const float4*)(A + (m0 + row) * 128 + kb + kq * 4);
            As[kq * 4 + 0][row] = av.x; As[kq * 4 + 1][row] = av.y;
            As[kq * 4 + 2][row] = av.z; As[kq * 4 + 3][row] = av.w;
            float4 bv = *(const float4*)(W + (size_t)(n0 + row) * 128 + kb + kq * 4);
            Bs[kq * 4 + 0][row] = bv.x; Bs[kq * 4 + 1][row] = bv.y;
            Bs[kq * 4 + 2][row] = bv.z; Bs[kq * 4 + 3][row] = bv.w;
        }
        __syncthreads();
        #pragma unroll
        for (int k = 0; k < 32; ++k) {
            float4 a4 = *(const float4*)&As[k][ty * 4];
            float4 b4 = *(const float4*)&Bs[k][tx * 4];
            float a_[4] = {a4.x, a4.y, a4.z, a4.w};
            float b_[4] = {b4.x, b4.y, b4.z, b4.w};
            #pragma unroll
            for (int i = 0; i < 4; ++i)
                #pragma unroll
                for (int j = 0; j < 4; ++j)
                    acc[i][j] += a_[i] * b_[j];
        }
        __syncthreads();
    }

    float4 bb = *(const float4*)(bias + n0 + tx * 4);
    float bi[4] = {bb.x, bb.y, bb.z, bb.w};
    #pragma unroll
    for (int i = 0; i < 4; ++i) {
        float4 o;
        o.x = acc[i][0] + bi[0]; o.y = acc[i][1] + bi[1];
        o.z = acc[i][2] + bi[2]; o.w = acc[i][3] + bi[3];
        *(float4*)(C + (m0 + ty * 4 + i) * G3_ + n0 + tx * 4) = o;
    }
}

// One block (1024 threads, 16 waves, 4 waves/SIMD) per batch element.
// Thread (w=tid>>6, lane): j = 8w + (lane>>3) in [0,128); k-chunk s = lane&7
// covers k in [16s, 16s+16). Each thread: 3 gate rows x 16 k = 48 FMAs.
// Reduction over s via shfl_xor 1/2/4 (row-local, no cross-row permutes).
// h double-buffered in LDS [8][20] (chunk-padded, conflict-free);
// ONE raw s_barrier per step, lgkm-only drain (global ops stay in flight).
__global__ __launch_bounds__(1024, 4) void gru_seq(const float* __restrict__ gi,
                                                   const float* __restrict__ Whh,
                                                   const float* __restrict__ bhh,
                                                   float* __restrict__ hout)
{
    __shared__ alignas(16) float hbuf[2][8][20];   // chunk s at [s][0..15]

    const int tid = threadIdx.x;
    const int b = blockIdx.x;
    const int w = tid >> 6, lane = tid & 63;
    const int j = 8 * w + (lane >> 3);
    const int s = lane & 7;

    // per-thread weights: rows j (r), 128+j (z), 256+j (n), cols [16s,16s+16)
    float wr[16], wz[16], wn[16];
    {
        const float4* p0 = (const float4*)(Whh + (size_t)j * 128 + s * 16);
        const float4* p1 = (const float4*)(Whh + (size_t)(128 + j) * 128 + s * 16);
        const float4* p2 = (const float4*)(Whh + (size_t)(256 + j) * 128 + s * 16);
        #pragma unroll
        for (int q = 0; q < 4; ++q) {
            float4 v0 = p0[q], v1 = p1[q], v2 = p2[q];
            wr[4*q+0]=v0.x; wr[4*q+1]=v0.y; wr[4*q+2]=v0.z; wr[4*q+3]=v0.w;
            wz[4*q+0]=v1.x; wz[4*q+1]=v1.y; wz[4*q+2]=v1.z; wz[4*q+3]=v1.w;
            wn[4*q+0]=v2.x; wn[4*q+1]=v2.y; wn[4*q+2]=v2.z; wn[4*q+3]=v2.w;
        }
    }
    const float br = bhh[j], bz = bhh[128 + j], bn = bhh[256 + j];

    if (tid < H_) hbuf[0][tid >> 4][tid & 15] = 0.f;
    __syncthreads();

    const float* gbase = gi + (size_t)b * T_ * G3_ + j;
    float* hop = hout + (size_t)b * T_ * H_;

    // prefetch t=0 gate inputs (only the finalizing s==0 lanes need them)
    float gr = 0.f, gz = 0.f, gn = 0.f;
    if (s == 0) { gr = gbase[0]; gz = gbase[128]; gn = gbase[256]; }

    float hprev = 0.f;

    for (int t = 0; t < T_; ++t) {
        const int p = t & 1;
        const float4* hv = (const float4*)(&hbuf[p][s][0]);
        float4 h0 = hv[0], h1 = hv[1], h2 = hv[2], h3 = hv[3];
        float hh[16] = {h0.x,h0.y,h0.z,h0.w, h1.x,h1.y,h1.z,h1.w,
                        h2.x,h2.y,h2.z,h2.w, h3.x,h3.y,h3.z,h3.w};
        float pr = 0.f, pz = 0.f, pn = 0.f;
        #pragma unroll
        for (int e = 0; e < 16; ++e) {
            pr += wr[e] * hh[e];
            pz += wz[e] * hh[e];
            pn += wn[e] * hh[e];
        }
        // reduce over the 8 k-chunks: lane-xor 1,2,4 (row-local)
        pr += __shfl_xor(pr, 1); pr += __shfl_xor(pr, 2); pr += __shfl_xor(pr, 4);
        pz += __shfl_xor(pz, 1); pz += __shfl_xor(pz, 2); pz += __shfl_xor(pz, 4);
        pn += __shfl_xor(pn, 1); pn += __shfl_xor(pn, 2); pn += __shfl_xor(pn, 4);

        if (s == 0) {
            float r  = sigm(gr + pr + br);
            float z  = sigm(gz + pz + bz);
            float nn = tanh_f(gn + r * (pn + bn));
            float hnew = (1.f - z) * nn + z * hprev;
            hprev = hnew;
            hbuf[p ^ 1][j >> 4][j & 15] = hnew;
            hop[(size_t)t * H_ + j] = hnew;   // fire-and-forget

            // prefetch next step's gate inputs
            int tn = (t + 1 < T_) ? t + 1 : t;
            const float* gp = gbase + (size_t)tn * G3_;
            gr = gp[0]; gz = gp[128]; gn = gp[256];
        }

        // LDS-only drain + raw barrier: do NOT drain vmcnt (stores/prefetch
        // stay in flight across the barrier).
        asm volatile("s_waitcnt lgkmcnt(0)" ::: "memory");
        __builtin_amdgcn_s_barrier();
    }
}

// One wave per sample: a = h2·W1[reg] + b1[reg]; SiLU; corr = a·W2[reg] + b2[reg]
__global__ __launch_bounds__(256) void head_k(const float* __restrict__ h2,
                                              const float* __restrict__ x,
                                              const int* __restrict__ regime,
                                              const float* __restrict__ W1,
                                              const float* __restrict__ b1,
                                              const float* __restrict__ W2,
                                              const float* __restrict__ b2,
                                              const float* __restrict__ lag_scale,
                                              const float* __restrict__ lag_bias,
                                              float* __restrict__ out)
{
    __shared__ alignas(16) float hrow[4][128];
    const int tid = threadIdx.x;
    const int wv = tid >> 6, lane = tid & 63;
    const size_t s = (size_t)blockIdx.x * 4 + wv;
    const int reg = regime[s];

    if (lane < 32)
        ((float4*)hrow[wv])[lane] = ((const float4*)(h2 + s * H_))[lane];
    __syncthreads();

    float acc = b1[reg * K_ + lane];
    const float* Wp = W1 + (size_t)reg * H_ * K_ + lane;
    const float4* h4p = (const float4*)hrow[wv];
    #pragma unroll
    for (int q = 0; q < 32; ++q) {
        float4 h4 = h4p[q];
        acc += h4.x * Wp[(4 * q + 0) * K_];
        acc += h4.y * Wp[(4 * q + 1) * K_];
        acc += h4.z * Wp[(4 * q + 2) * K_];
        acc += h4.w * Wp[(4 * q + 3) * K_];
    }
    float silu = acc * sigm(acc);
    float v = silu * W2[reg * K_ + lane];
    #pragma unroll
    for (int m = 1; m < 64; m <<= 1) v += __shfl_xor(v, m);
    if (lane == 0) {
        float lag = lag_scale[0] * x[s * F_] + lag_bias[0];
        out[s] = lag + v + b2[reg];
    }
}

extern "C" void kernel_launch(void* const* d_in, const int* in_sizes, int n_in,
                              void* d_out, int out_size, void* d_ws, size_t ws_size,
                              hipStream_t stream) {
    const float* x         = (const float*)d_in[0];
    const int*   regime    = (const int*)d_in[1];
    const float* lag_scale = (const float*)d_in[2];
    const float* lag_bias  = (const float*)d_in[3];
    const float* Wih0      = (const float*)d_in[4];
    const float* Whh0      = (const float*)d_in[5];
    const float* bih0      = (const float*)d_in[6];
    const float* bhh0      = (const float*)d_in[7];
    const float* Wih1      = (const float*)d_in[8];
    const float* Whh1      = (const float*)d_in[9];
    const float* bih1      = (const float*)d_in[10];
    const float* bhh1      = (const float*)d_in[11];
    const float* W1        = (const float*)d_in[12];
    const float* b1        = (const float*)d_in[13];
    const float* W2        = (const float*)d_in[14];
    const float* b2        = (const float*)d_in[15];
    float* out = (float*)d_out;

    const size_t NT = (size_t)B_ * T_;               // 131072
    const size_t need = NT * G3_ * 4 + NT * H_ * 4;  // 256 MiB
    if (ws_size < need) {
        hipMemsetAsync(d_out, 0x7F, (size_t)out_size * 4, stream);
        return;
    }
    float* gi = (float*)d_ws;
    float* hb = gi + NT * G3_;                       // h1, then reused as h2

    dim3 ggrid(G3_ / 64, (int)(NT / 64));            // (6, 2048)
    gemm_gi<<<ggrid, 256, 0, stream>>>(x, Wih0, bih0, gi);
    gru_seq<<<B_, 1024, 0, stream>>>(gi, Whh0, bhh0, hb);
    gemm_gi<<<ggrid, 256, 0, stream>>>(hb, Wih1, bih1, gi);
    gru_seq<<<B_, 1024, 0, stream>>>(gi, Whh1, bhh1, hb);
    head_k<<<(int)(NT / 4), 256, 0, stream>>>(hb, x, regime, W1, b1, W2, b2,
                                              lag_scale, lag_bias, out);
}